// Round 10
// baseline (180.015 us; speedup 1.0000x reference)
//
#include <hip/hip_runtime.h>
#include <cstdint>
#include <cstddef>

// ---------------------------------------------------------------------------
// ChatGPTAttention: x[2,2048,1024] -> QKV proj -> causal MHA (16 heads, dk=64)
//                   -> O proj. bf16 MFMA pipeline, fp32 accumulate.
// Q pre-scaled by 1/8 in QKV-GEMM epilogue; V written transposed there (R14).
// LESSONS: (R5) LDS row stride mult of 8. (R6/R8) XOR swizzle for DMA LDS.
// (R11/R15) direct global frags fragment. (R18) split P buffers. (R19 FAILED)
// lag-1 PV spills. (R20 FAILED) direct-global V. (R21 NULL) per-CU balancing.
// (R22 WIN) 4-wave qxkv split 44.5->36.5. (R23 NEUTRAL) bt64 retile.
// (R24/R25 FAILED) 8-phase 256^2 QKV GEMM at K=1024: pipeline never
// amortizes; REVERTED to 2-barrier 128^2 (40.6us measured R9). (R26 NEUTRAL)
// 8-wave attn split = 4-wave -> chain-split saturated; per-tile cost is the
// FIXED barrier+DMA-drain: __syncthreads() emits vmcnt(0) draining the
// just-issued next-tile DMA (2700cyc/tile vs ~400 of pipe work).
// R27 v20: 3-DEEP K/V BUFFERS + COUNTED VMCNT (T4). Per iter: lgkmcnt(0);
// raw s_barrier; stage(t+2 -> buf[(t+2)%3]); vmcnt(4) (retires exactly tile
// t's 2 loads; 2 pre-loop Q loads retire first, in-order). Never vmcnt(0)
// in-loop -> DMA latency spans 2 iterations. Tail: dummy re-stage of tile t
// into the dead buffer (uniform per-thread vmcnt accounting). lgkmcnt(0)
// before each barrier orders pending ds_reads of the recycled buffer vs new
// DMA. LDS 58.2KB -> 2 blocks/CU (occupancy not binding per R16/R17).
// ---------------------------------------------------------------------------

typedef __attribute__((ext_vector_type(8))) short bf16x8;   // MFMA A/B frag
typedef __attribute__((ext_vector_type(4))) float f32x4;    // MFMA C/D frag
typedef __attribute__((ext_vector_type(4))) unsigned int u32x4;   // 16B copy
typedef __attribute__((ext_vector_type(4))) unsigned short u16x4; // 8B store
typedef __attribute__((ext_vector_type(8))) unsigned short u16x8; // 16B store

__device__ __forceinline__ unsigned short f2b(float f) {  // RNE f32->bf16
  unsigned int u = __float_as_uint(f);
  u = u + 0x7FFFu + ((u >> 16) & 1u);
  return (unsigned short)(u >> 16);
}
__device__ __forceinline__ unsigned short f2b_trunc(float f) {  // truncate
  return (unsigned short)(__float_as_uint(f) >> 16);
}

// async global->LDS DMA, 16B per lane; LDS dest = wave base + lane*16
__device__ __forceinline__ void gl_lds16(const unsigned short* g, unsigned short* s) {
  __builtin_amdgcn_global_load_lds((const __attribute__((address_space(1))) void*)g,
                                   (__attribute__((address_space(3))) void*)s, 16, 0, 0);
}

// ---------------- fp32 -> bf16, all three inputs in one launch -------------
__global__ __launch_bounds__(256) void cvt_all(const float* __restrict__ x,
                                               const float* __restrict__ wq,
                                               const float* __restrict__ wo,
                                               unsigned short* __restrict__ xb,
                                               unsigned short* __restrict__ wqb,
                                               unsigned short* __restrict__ wob) {
  const int bid = blockIdx.x;
  const float* in;
  unsigned short* out;
  int base;
  if (bid < 4096)      { in = x;  out = xb;  base = bid; }
  else if (bid < 7168) { in = wq; out = wqb; base = bid - 4096; }
  else                 { in = wo; out = wob; base = bid - 7168; }
  const int idx = (base * 256 + threadIdx.x) * 4;
  f32x4 v = *(const f32x4*)(in + idx);
  u16x4 r;
  r[0] = f2b(v[0]); r[1] = f2b(v[1]); r[2] = f2b(v[2]); r[3] = f2b(v[3]);
  *(u16x4*)(out + idx) = r;
}

// ---------------- GEMM: C[M,N] = (A[M,K] * W[N,K]^T + bias) * colscale -----
// 128x128 tile, BK=32, dbuf DMA (32KB LDS). V-column blocks (n0>=2048) write
// transposed into vt as packed u16x4. PROVEN R14 structure (40.6us measured).
__global__ __launch_bounds__(256) void gemm_bt(const unsigned short* __restrict__ A,
                                               const unsigned short* __restrict__ W,
                                               const float* __restrict__ bias,
                                               unsigned short* __restrict__ Cb,
                                               unsigned short* __restrict__ vtb,
                                               int M, int N, int K, int qcols) {
  __shared__ unsigned short As[2][128 * 32];
  __shared__ unsigned short Bs[2][128 * 32];
  const int tid  = threadIdx.x;
  const int lane = tid & 63;
  const int w    = tid >> 6;
  const int wy   = w >> 1, wx = w & 1;
  const int l15  = lane & 15, quad = lane >> 4;
  const int xr2  = (l15 >> 1) & 3;
  const int m0 = blockIdx.y * 128, n0 = blockIdx.x * 128;

  const unsigned short* gA[2];
  const unsigned short* gB[2];
  int off[2];
#pragma unroll
  for (int p = 0; p < 2; ++p) {
    const int c = tid + p * 256;
    const int r = c >> 2;
    const int srcc = (c & 3) ^ ((r >> 1) & 3);
    gA[p] = A + (size_t)(m0 + r) * K + srcc * 8;
    gB[p] = W + (size_t)(n0 + r) * K + srcc * 8;
    off[p] = c * 8;
  }

  f32x4 acc[4][4];
#pragma unroll
  for (int i = 0; i < 4; ++i)
#pragma unroll
    for (int j = 0; j < 4; ++j) acc[i][j] = (f32x4){0.f, 0.f, 0.f, 0.f};

#pragma unroll
  for (int p = 0; p < 2; ++p) {
    gl_lds16(gA[p], &As[0][off[p]]);
    gl_lds16(gB[p], &Bs[0][off[p]]);
  }

  const int NIT = K >> 5;
  for (int it = 0; it < NIT; ++it) {
    __syncthreads();
    const int cur = it & 1;
    if (it + 1 < NIT) {
      const int kt = (it + 1) << 5;
#pragma unroll
      for (int p = 0; p < 2; ++p) {
        gl_lds16(gA[p] + kt, &As[cur ^ 1][off[p]]);
        gl_lds16(gB[p] + kt, &Bs[cur ^ 1][off[p]]);
      }
    }
    const unsigned short* Ac = As[cur];
    const unsigned short* Bc = Bs[cur];
    bf16x8 af[4], bfr[4];
#pragma unroll
    for (int i = 0; i < 4; ++i)
      af[i] = *(const bf16x8*)&Ac[(wy * 64 + i * 16 + l15) * 32 + (quad ^ xr2) * 8];
#pragma unroll
    for (int j = 0; j < 4; ++j)
      bfr[j] = *(const bf16x8*)&Bc[(wx * 64 + j * 16 + l15) * 32 + (quad ^ xr2) * 8];
#pragma unroll
    for (int i = 0; i < 4; ++i)
#pragma unroll
      for (int j = 0; j < 4; ++j)
        acc[i][j] = __builtin_amdgcn_mfma_f32_16x16x32_bf16(af[i], bfr[j], acc[i][j], 0, 0, 0);
  }

  const bool vblock = (n0 >= 2048);  // block-uniform
#pragma unroll
  for (int i = 0; i < 4; ++i) {
    const int row = m0 + wy * 64 + i * 16 + quad * 4;
#pragma unroll
    for (int j = 0; j < 4; ++j) {
      const int col = n0 + wx * 64 + j * 16 + l15;
      const float bv = bias[col];
      if (!vblock) {
        const float sc = (col < qcols) ? 0.125f : 1.0f;
#pragma unroll
        for (int r = 0; r < 4; ++r)
          Cb[(size_t)(row + r) * N + col] = f2b((acc[i][j][r] + bv) * sc);
      } else {
        const int hd = col - 2048;
        const int bb = row >> 11, s = row & 2047;
        u16x4 ov;
#pragma unroll
        for (int r = 0; r < 4; ++r) ov[r] = f2b(acc[i][j][r] + bv);
        *(u16x4*)(vtb + ((size_t)(bb * 1024 + hd)) * 2048 + s) = ov;
      }
    }
  }
}

// ---------------- GEMM 128x64 tile, fp32 out (O-projection) ----------------
// R23 config. Grid (16,32)=512 blocks, LDS 48KB.
__global__ __launch_bounds__(256) void gemm_bt64(const unsigned short* __restrict__ A,
                                                 const unsigned short* __restrict__ W,
                                                 const float* __restrict__ bias,
                                                 float* __restrict__ Cf,
                                                 int M, int N, int K) {
  __shared__ unsigned short As[2][128 * 64];
  __shared__ unsigned short Bs[2][64 * 64];
  const int tid  = threadIdx.x;
  const int lane = tid & 63;
  const int w    = tid >> 6;
  const int wy   = w >> 1, wx = w & 1;
  const int l15  = lane & 15, quad = lane >> 4;
  const int xr   = l15 & 7;
  const int m0 = blockIdx.y * 128, n0 = blockIdx.x * 64;

  const unsigned short* gA[4];
  int offA[4];
#pragma unroll
  for (int p = 0; p < 4; ++p) {
    const int c = tid + p * 256;
    const int r = c >> 3;
    const int sc = ((c & 7) ^ (r & 7)) * 8;
    gA[p] = A + (size_t)(m0 + r) * K + sc;
    offA[p] = c * 8;
  }
  const unsigned short* gB[2];
  int offB[2];
#pragma unroll
  for (int p = 0; p < 2; ++p) {
    const int c = tid + p * 256;
    const int r = c >> 3;
    const int sc = ((c & 7) ^ (r & 7)) * 8;
    gB[p] = W + (size_t)(n0 + r) * K + sc;
    offB[p] = c * 8;
  }

  f32x4 acc[4][2];
#pragma unroll
  for (int i = 0; i < 4; ++i)
#pragma unroll
    for (int j = 0; j < 2; ++j) acc[i][j] = (f32x4){0.f, 0.f, 0.f, 0.f};

#pragma unroll
  for (int p = 0; p < 4; ++p) gl_lds16(gA[p], &As[0][offA[p]]);
#pragma unroll
  for (int p = 0; p < 2; ++p) gl_lds16(gB[p], &Bs[0][offB[p]]);

  const int NIT = K >> 6;
  for (int it = 0; it < NIT; ++it) {
    __syncthreads();
    const int cur = it & 1;
    if (it + 1 < NIT) {
      const int kt = (it + 1) << 6;
#pragma unroll
      for (int p = 0; p < 4; ++p) gl_lds16(gA[p] + kt, &As[cur ^ 1][offA[p]]);
#pragma unroll
      for (int p = 0; p < 2; ++p) gl_lds16(gB[p] + kt, &Bs[cur ^ 1][offB[p]]);
    }
    const unsigned short* Ac = As[cur];
    const unsigned short* Bc = Bs[cur];
#pragma unroll
    for (int kc = 0; kc < 2; ++kc) {
      bf16x8 af[4], bfr[2];
#pragma unroll
      for (int i = 0; i < 4; ++i)
        af[i] = *(const bf16x8*)&Ac[(wy * 64 + i * 16 + l15) * 64 + ((kc * 4 + quad) ^ xr) * 8];
#pragma unroll
      for (int j = 0; j < 2; ++j)
        bfr[j] = *(const bf16x8*)&Bc[(wx * 32 + j * 16 + l15) * 64 + ((kc * 4 + quad) ^ xr) * 8];
#pragma unroll
      for (int i = 0; i < 4; ++i)
#pragma unroll
        for (int j = 0; j < 2; ++j)
          acc[i][j] = __builtin_amdgcn_mfma_f32_16x16x32_bf16(af[i], bfr[j], acc[i][j], 0, 0, 0);
    }
  }

#pragma unroll
  for (int i = 0; i < 4; ++i) {
    const int row = m0 + wy * 64 + i * 16 + quad * 4;
#pragma unroll
    for (int j = 0; j < 2; ++j) {
      const int col = n0 + wx * 32 + j * 16 + l15;
      const float bv = bias[col];
#pragma unroll
      for (int r = 0; r < 4; ++r)
        Cf[(size_t)(row + r) * N + col] = acc[i][j][r] + bv;
    }
  }
}

// ---------------- flash attention v20: v19 + 3-buf counted vmcnt -----------
// Block = 8 waves (wq 0..3 x wk 0..1), 512 thr; grid (bh 32, y 32). Wave:
// 16 q x 32 kv. Staging: 1 K + 1 V gl_lds per thread per tile into 3 rotating
// buffers; per iter {lgkmcnt(0); s_barrier; stage(t+2); vmcnt(4)} — tile t's
// loads retired, t+1/t+2 in flight. Dummy re-stage of tile t at the tail
// keeps per-thread vmcnt uniform. Combine via dead Ks/Vs after full drain.
__global__ __launch_bounds__(512, 4) void attn_fwd(const unsigned short* __restrict__ qkv,
                                                   const unsigned short* __restrict__ vt,
                                                   unsigned short* __restrict__ o) {
  __shared__ unsigned short Ks[3][64 * 64];
  __shared__ unsigned short Vs[3][64 * 64];
  __shared__ unsigned short pbuf[8][16 * 40];  // [wave][16 q x (32+8) kv]
  const int tid  = threadIdx.x;
  const int lane = tid & 63;
  const int w    = tid >> 6;          // 8 waves
  const int wq   = w & 3;             // q-quarter (16 q)
  const int wk   = w >> 2;            // kv-half (32 kv)
  const int l15  = lane & 15, quad = lane >> 4;
  const int xr   = l15 & 7;
  const int bh = blockIdx.x, b = bh >> 4, h = bh & 15;
  const int y  = (int)blockIdx.y;
  const int qt = (y < 16) ? y : 47 - y;  // per-CU balanced (R21)
  const int q0 = qt * 64;
  const int T = qt + 1;
  const int qs = q0 + wq * 16;        // this wave's q base (16 rows)

  // DMA staging: 512 chunks per 64x64 tile / 512 threads = 1/thread/array.
  const int r  = tid >> 3;
  const int sc = ((tid & 7) ^ (r & 7)) * 8;
  const unsigned short* gKd = qkv + (size_t)(b * 2048 + r) * 3072 + 1024 + h * 64 + sc;
  const unsigned short* gVd = vt + (size_t)(bh * 64 + r) * 2048 + sc;
  const int doff = tid * 8;

  const unsigned short* qr = qkv + (size_t)(b * 2048 + qs + l15) * 3072 + h * 64;
  const bf16x8 bq[2] = { *(const bf16x8*)(qr + quad * 8),
                         *(const bf16x8*)(qr + 32 + quad * 8) };

  bf16x8 vones;
#pragma unroll
  for (int k = 0; k < 8; ++k) vones[k] = (short)0x3F80;  // bf16 1.0

  f32x4 acc[4];      // [d-tile], PARTIAL over this wave's kv-half
#pragma unroll
  for (int j = 0; j < 4; ++j) acc[j] = (f32x4){0.f, 0.f, 0.f, 0.f};
  f32x4 accL = (f32x4){0.f, 0.f, 0.f, 0.f};

  unsigned short* P = pbuf[w];

  // prologue: stage tiles 0 (buf0) and 1 (buf1). Tile 1 addresses are
  // in-bounds for all qt (kv rows 64..127 < 2048).
  gl_lds16(gKd, &Ks[0][doff]);
  gl_lds16(gVd, &Vs[0][doff]);
  gl_lds16(gKd + (size_t)64 * 3072, &Ks[1][doff]);
  gl_lds16(gVd + 64, &Vs[1][doff]);

  for (int t = 0; t < T; ++t) {
    // own LDS reads of the recycled buffer are drained before the barrier
    asm volatile("s_waitcnt lgkmcnt(0)" ::: "memory");
    __builtin_amdgcn_s_barrier();
    // stage t+2 (or dummy re-stage of t into the dead buffer at the tail)
    {
      const int tn = (t + 2 < T) ? (t + 2) : t;
      const int bn = (t + 2) % 3;
      gl_lds16(gKd + (size_t)tn * 64 * 3072, &Ks[bn][doff]);
      gl_lds16(gVd + tn * 64, &Vs[bn][doff]);
    }
    asm volatile("s_waitcnt vmcnt(4)" ::: "memory");  // tile t resident
    __builtin_amdgcn_sched_barrier(0);
    const unsigned short* Kc = Ks[t % 3];
    const unsigned short* Vc = Vs[t % 3];
    const int kv0 = t * 64 + wk * 32;   // this wave's kv base

    // ---- S^T[kv][q] = K Q^T, this wave's 32 kv x 16 q ----
    f32x4 st[2];
#pragma unroll
    for (int n = 0; n < 2; ++n) {
      const int row = wk * 32 + n * 16 + l15;
      const bf16x8 kA0 = *(const bf16x8*)&Kc[row * 64 + ((quad) ^ xr) * 8];
      const bf16x8 kA1 = *(const bf16x8*)&Kc[row * 64 + ((4 + quad) ^ xr) * 8];
      f32x4 z = (f32x4){0.f, 0.f, 0.f, 0.f};
      z = __builtin_amdgcn_mfma_f32_16x16x32_bf16(kA0, bq[0], z, 0, 0, 0);
      z = __builtin_amdgcn_mfma_f32_16x16x32_bf16(kA1, bq[1], z, 0, 0, 0);
      st[n] = z;
    }
    // ---- V^T A-frags for this kv-half ----
    bf16x8 av[4];
#pragma unroll
    for (int j = 0; j < 4; ++j) {
      const int row = j * 16 + l15;
      av[j] = *(const bf16x8*)&Vc[row * 64 + ((wk * 4 + quad) ^ xr) * 8];
    }
    // ---- mask/exp + P write ----
    if (kv0 + 31 > qs) {
      const int qrow = qs + l15;
#pragma unroll
      for (int n = 0; n < 2; ++n)
#pragma unroll
        for (int rr = 0; rr < 4; ++rr)
          if (kv0 + n * 16 + quad * 4 + rr > qrow) st[n][rr] = -1e30f;
    }
#pragma unroll
    for (int n = 0; n < 2; ++n) {
#pragma unroll
      for (int rr = 0; rr < 4; ++rr) st[n][rr] = __expf(st[n][rr]);
      u16x4 pw;
      pw[0] = f2b_trunc(st[n][0]); pw[1] = f2b_trunc(st[n][1]);
      pw[2] = f2b_trunc(st[n][2]); pw[3] = f2b_trunc(st[n][3]);
      *(u16x4*)&P[l15 * 40 + n * 16 + quad * 4] = pw;
    }
    // ---- Pr + PV (K=32 contraction) ----
    {
      const bf16x8 bp = *(const bf16x8*)&P[l15 * 40 + quad * 8];
      accL = __builtin_amdgcn_mfma_f32_16x16x32_bf16(vones, bp, accL, 0, 0, 0);
#pragma unroll
      for (int j = 0; j < 4; ++j)
        acc[j] = __builtin_amdgcn_mfma_f32_16x16x32_bf16(av[j], bp, acc[j], 0, 0, 0);
    }
  }

  // ---- full drain, then cross-wave kv-half combine in dead K/V buffers ----
  asm volatile("s_waitcnt vmcnt(0) lgkmcnt(0)" ::: "memory");
  __builtin_amdgcn_s_barrier();
  float* cmbA = (float*)&Ks[0][0];   // 16 frags x 1KB = 16KB (Ks[0..1])
  float* cmbL = (float*)&Vs[0][0];   // 4 x 64 floats = 1KB
  if (wk == 1) {
    cmbL[wq * 64 + lane] = accL[0];
#pragma unroll
    for (int j = 0; j < 4; ++j)
      *(f32x4*)&cmbA[((wq * 4 + j) << 8) + lane * 4] = acc[j];
  }
  __syncthreads();
  if (wk == 0) {
    const float lsum = accL[0] + cmbL[wq * 64 + lane];
    const float inv = 1.0f / lsum;
    const int qrow = qs + l15;
    unsigned short* orow = o + (size_t)(b * 2048 + qrow) * 1024 + h * 64;
#pragma unroll
    for (int j = 0; j < 4; ++j) {
      const f32x4 oth = *(const f32x4*)&cmbA[((wq * 4 + j) << 8) + lane * 4];
      u16x4 ov;
      ov[0] = f2b((acc[j][0] + oth[0]) * inv);
      ov[1] = f2b((acc[j][1] + oth[1]) * inv);
      ov[2] = f2b((acc[j][2] + oth[2]) * inv);
      ov[3] = f2b((acc[j][3] + oth[3]) * inv);
      *(u16x4*)(orow + j * 16 + quad * 4) = ov;
    }
  }
}

// ---------------------------------------------------------------------------
extern "C" void kernel_launch(void* const* d_in, const int* in_sizes, int n_in,
                              void* d_out, int out_size, void* d_ws, size_t ws_size,
                              hipStream_t stream) {
  const float* x       = (const float*)d_in[0];
  // d_in[1] = mask: causal tril by construction; implemented analytically.
  const float* w_qkv_w = (const float*)d_in[2];
  const float* w_qkv_b = (const float*)d_in[3];
  const float* w_o_w   = (const float*)d_in[4];
  const float* w_o_b   = (const float*)d_in[5];
  float* out = (float*)d_out;

  unsigned short* ws    = (unsigned short*)d_ws;
  unsigned short* xb    = ws;                                  // 4096*1024
  unsigned short* wqb   = xb   + (size_t)4096 * 1024;          // 3072*1024
  unsigned short* wob   = wqb  + (size_t)3072 * 1024;          // 1024*1024
  unsigned short* qkvb  = wob  + (size_t)1024 * 1024;          // 4096*3072
  unsigned short* vtb   = qkvb + (size_t)4096 * 3072;          // 2048*2048
  unsigned short* attnb = vtb  + (size_t)2048 * 2048;          // 4096*1024

  cvt_all<<<8192, 256, 0, stream>>>(x, w_qkv_w, w_o_w, xb, wqb, wob);
  gemm_bt<<<dim3(24, 32), 256, 0, stream>>>(xb, wqb, w_qkv_b, qkvb, vtb, 4096, 3072, 1024, 1024);
  attn_fwd<<<dim3(32, 32), 512, 0, stream>>>(qkvb, vtb, attnb);
  gemm_bt64<<<dim3(16, 32), 256, 0, stream>>>(attnb, wob, w_o_b, out, 4096, 1024, 1024);
}

// Round 11
// 177.379 us; speedup vs baseline: 1.0149x; 1.0149x over previous
//
#include <hip/hip_runtime.h>
#include <cstdint>
#include <cstddef>

// ---------------------------------------------------------------------------
// ChatGPTAttention: x[2,2048,1024] -> QKV proj -> causal MHA (16 heads, dk=64)
//                   -> O proj. bf16 MFMA pipeline, fp32 accumulate.
// Q pre-scaled by 1/8 in QKV-GEMM epilogue; V written transposed there (R14).
// LESSONS: (R5) LDS row stride mult of 8. (R6/R8) XOR swizzle for DMA LDS.
// (R11/R15) direct global frags fragment. (R18) split P buffers. (R19 FAILED)
// lag-1 PV spills. (R20 FAILED) direct-global V. (R21 NULL) per-CU balancing.
// (R22 WIN) 4-wave qxkv split 44.5->36.5. (R23 NEUTRAL) bt64 retile.
// (R24/R25 FAILED) 8-phase 256^2 QKV GEMM at K=1024. (R26 NEUTRAL) 8-wave
// attn split. (R27 NEUTRAL/-0.8us) 3-buf counted-vmcnt on attn: DMA drain is
// NOT attn's constraint (joins occupancy/traffic/chain-split as falsified);
// attn REVERTED to v19.
// R28: apply 3-buf + counted vmcnt to GEMM_BT instead — the guide documents
// the vmcnt(0)-before-barrier drain as THIS structure's ~20% stall, and
// gemm_bt's signature (Mfma 23%, VALU 20%, all pipes idle, ~1015cyc/iter vs
// ~250 of work at 3 blk/CU) matches. 3 x 8KB buffers per array (48KB total,
// still 3 blk/CU). Per iter: lgkmcnt(0); s_barrier; stage(it+2 -> (it+2)%3);
// vmcnt(8) = retire exactly tile it's 4 loads (it+1/it+2's 8 stay in
// flight). Tail: dummy re-stage of tile it into the dead buffer (uniform
// counts). vmcnt(0) before epilogue (in-flight DMA must not outlive LDS).
// Count walk: entry it -> outstanding {t,t+1}=8; +4 staged = 12; vmcnt(8)
// retires t. it=30/31 dummies: bn=(it+2)%3 holds tile it-1, consumed and
// barrier-synced. Machinery (rotation+counted wait) proven correct in R27.
// ---------------------------------------------------------------------------

typedef __attribute__((ext_vector_type(8))) short bf16x8;   // MFMA A/B frag
typedef __attribute__((ext_vector_type(4))) float f32x4;    // MFMA C/D frag
typedef __attribute__((ext_vector_type(4))) unsigned int u32x4;   // 16B copy
typedef __attribute__((ext_vector_type(4))) unsigned short u16x4; // 8B store
typedef __attribute__((ext_vector_type(8))) unsigned short u16x8; // 16B store

__device__ __forceinline__ unsigned short f2b(float f) {  // RNE f32->bf16
  unsigned int u = __float_as_uint(f);
  u = u + 0x7FFFu + ((u >> 16) & 1u);
  return (unsigned short)(u >> 16);
}
__device__ __forceinline__ unsigned short f2b_trunc(float f) {  // truncate
  return (unsigned short)(__float_as_uint(f) >> 16);
}

// async global->LDS DMA, 16B per lane; LDS dest = wave base + lane*16
__device__ __forceinline__ void gl_lds16(const unsigned short* g, unsigned short* s) {
  __builtin_amdgcn_global_load_lds((const __attribute__((address_space(1))) void*)g,
                                   (__attribute__((address_space(3))) void*)s, 16, 0, 0);
}

// ---------------- fp32 -> bf16, all three inputs in one launch -------------
__global__ __launch_bounds__(256) void cvt_all(const float* __restrict__ x,
                                               const float* __restrict__ wq,
                                               const float* __restrict__ wo,
                                               unsigned short* __restrict__ xb,
                                               unsigned short* __restrict__ wqb,
                                               unsigned short* __restrict__ wob) {
  const int bid = blockIdx.x;
  const float* in;
  unsigned short* out;
  int base;
  if (bid < 4096)      { in = x;  out = xb;  base = bid; }
  else if (bid < 7168) { in = wq; out = wqb; base = bid - 4096; }
  else                 { in = wo; out = wob; base = bid - 7168; }
  const int idx = (base * 256 + threadIdx.x) * 4;
  f32x4 v = *(const f32x4*)(in + idx);
  u16x4 r;
  r[0] = f2b(v[0]); r[1] = f2b(v[1]); r[2] = f2b(v[2]); r[3] = f2b(v[3]);
  *(u16x4*)(out + idx) = r;
}

// ---------------- GEMM: C[M,N] = (A[M,K] * W[N,K]^T + bias) * colscale -----
// 128x128 tile, BK=32, R28: 3-deep rotating DMA buffers + counted vmcnt
// (48KB LDS, 3 blocks/CU). V-column blocks (n0>=2048) write transposed vt.
__global__ __launch_bounds__(256) void gemm_bt(const unsigned short* __restrict__ A,
                                               const unsigned short* __restrict__ W,
                                               const float* __restrict__ bias,
                                               unsigned short* __restrict__ Cb,
                                               unsigned short* __restrict__ vtb,
                                               int M, int N, int K, int qcols) {
  __shared__ unsigned short As[3][128 * 32];
  __shared__ unsigned short Bs[3][128 * 32];
  const int tid  = threadIdx.x;
  const int lane = tid & 63;
  const int w    = tid >> 6;
  const int wy   = w >> 1, wx = w & 1;
  const int l15  = lane & 15, quad = lane >> 4;
  const int xr2  = (l15 >> 1) & 3;
  const int m0 = blockIdx.y * 128, n0 = blockIdx.x * 128;

  const unsigned short* gA[2];
  const unsigned short* gB[2];
  int off[2];
#pragma unroll
  for (int p = 0; p < 2; ++p) {
    const int c = tid + p * 256;
    const int r = c >> 2;
    const int srcc = (c & 3) ^ ((r >> 1) & 3);
    gA[p] = A + (size_t)(m0 + r) * K + srcc * 8;
    gB[p] = W + (size_t)(n0 + r) * K + srcc * 8;
    off[p] = c * 8;
  }

  f32x4 acc[4][4];
#pragma unroll
  for (int i = 0; i < 4; ++i)
#pragma unroll
    for (int j = 0; j < 4; ++j) acc[i][j] = (f32x4){0.f, 0.f, 0.f, 0.f};

  // prologue: stage tile 0 -> buf0, tile 1 -> buf1 (8 loads outstanding)
#pragma unroll
  for (int p = 0; p < 2; ++p) {
    gl_lds16(gA[p], &As[0][off[p]]);
    gl_lds16(gB[p], &Bs[0][off[p]]);
  }
#pragma unroll
  for (int p = 0; p < 2; ++p) {
    gl_lds16(gA[p] + 32, &As[1][off[p]]);
    gl_lds16(gB[p] + 32, &Bs[1][off[p]]);
  }

  const int NIT = K >> 5;   // 32
  for (int it = 0; it < NIT; ++it) {
    // own ds_reads of the recycled buffer drained before the barrier
    asm volatile("s_waitcnt lgkmcnt(0)" ::: "memory");
    __builtin_amdgcn_s_barrier();
    // stage it+2 (or dummy re-stage of tile it into the dead buffer)
    {
      const int stg = (it + 2 < NIT) ? (it + 2) : it;
      const int bn  = (it + 2) % 3;
      const int kt  = stg << 5;
#pragma unroll
      for (int p = 0; p < 2; ++p) {
        gl_lds16(gA[p] + kt, &As[bn][off[p]]);
        gl_lds16(gB[p] + kt, &Bs[bn][off[p]]);
      }
    }
    asm volatile("s_waitcnt vmcnt(8)" ::: "memory");  // tile it resident
    __builtin_amdgcn_sched_barrier(0);
    const unsigned short* Ac = As[it % 3];
    const unsigned short* Bc = Bs[it % 3];
    bf16x8 af[4], bfr[4];
#pragma unroll
    for (int i = 0; i < 4; ++i)
      af[i] = *(const bf16x8*)&Ac[(wy * 64 + i * 16 + l15) * 32 + (quad ^ xr2) * 8];
#pragma unroll
    for (int j = 0; j < 4; ++j)
      bfr[j] = *(const bf16x8*)&Bc[(wx * 64 + j * 16 + l15) * 32 + (quad ^ xr2) * 8];
#pragma unroll
    for (int i = 0; i < 4; ++i)
#pragma unroll
      for (int j = 0; j < 4; ++j)
        acc[i][j] = __builtin_amdgcn_mfma_f32_16x16x32_bf16(af[i], bfr[j], acc[i][j], 0, 0, 0);
  }
  // drain dummies: in-flight DMA must not land in deallocated LDS
  asm volatile("s_waitcnt vmcnt(0)" ::: "memory");

  const bool vblock = (n0 >= 2048);  // block-uniform
#pragma unroll
  for (int i = 0; i < 4; ++i) {
    const int row = m0 + wy * 64 + i * 16 + quad * 4;
#pragma unroll
    for (int j = 0; j < 4; ++j) {
      const int col = n0 + wx * 64 + j * 16 + l15;
      const float bv = bias[col];
      if (!vblock) {
        const float sc = (col < qcols) ? 0.125f : 1.0f;
#pragma unroll
        for (int r = 0; r < 4; ++r)
          Cb[(size_t)(row + r) * N + col] = f2b((acc[i][j][r] + bv) * sc);
      } else {
        const int hd = col - 2048;
        const int bb = row >> 11, s = row & 2047;
        u16x4 ov;
#pragma unroll
        for (int r = 0; r < 4; ++r) ov[r] = f2b(acc[i][j][r] + bv);
        *(u16x4*)(vtb + ((size_t)(bb * 1024 + hd)) * 2048 + s) = ov;
      }
    }
  }
}

// ---------------- GEMM 128x64 tile, fp32 out (O-projection) ----------------
// R23 config. Grid (16,32)=512 blocks, LDS 48KB.
__global__ __launch_bounds__(256) void gemm_bt64(const unsigned short* __restrict__ A,
                                                 const unsigned short* __restrict__ W,
                                                 const float* __restrict__ bias,
                                                 float* __restrict__ Cf,
                                                 int M, int N, int K) {
  __shared__ unsigned short As[2][128 * 64];
  __shared__ unsigned short Bs[2][64 * 64];
  const int tid  = threadIdx.x;
  const int lane = tid & 63;
  const int w    = tid >> 6;
  const int wy   = w >> 1, wx = w & 1;
  const int l15  = lane & 15, quad = lane >> 4;
  const int xr   = l15 & 7;
  const int m0 = blockIdx.y * 128, n0 = blockIdx.x * 64;

  const unsigned short* gA[4];
  int offA[4];
#pragma unroll
  for (int p = 0; p < 4; ++p) {
    const int c = tid + p * 256;
    const int r = c >> 3;
    const int sc = ((c & 7) ^ (r & 7)) * 8;
    gA[p] = A + (size_t)(m0 + r) * K + sc;
    offA[p] = c * 8;
  }
  const unsigned short* gB[2];
  int offB[2];
#pragma unroll
  for (int p = 0; p < 2; ++p) {
    const int c = tid + p * 256;
    const int r = c >> 3;
    const int sc = ((c & 7) ^ (r & 7)) * 8;
    gB[p] = W + (size_t)(n0 + r) * K + sc;
    offB[p] = c * 8;
  }

  f32x4 acc[4][2];
#pragma unroll
  for (int i = 0; i < 4; ++i)
#pragma unroll
    for (int j = 0; j < 2; ++j) acc[i][j] = (f32x4){0.f, 0.f, 0.f, 0.f};

#pragma unroll
  for (int p = 0; p < 4; ++p) gl_lds16(gA[p], &As[0][offA[p]]);
#pragma unroll
  for (int p = 0; p < 2; ++p) gl_lds16(gB[p], &Bs[0][offB[p]]);

  const int NIT = K >> 6;
  for (int it = 0; it < NIT; ++it) {
    __syncthreads();
    const int cur = it & 1;
    if (it + 1 < NIT) {
      const int kt = (it + 1) << 6;
#pragma unroll
      for (int p = 0; p < 4; ++p) gl_lds16(gA[p] + kt, &As[cur ^ 1][offA[p]]);
#pragma unroll
      for (int p = 0; p < 2; ++p) gl_lds16(gB[p] + kt, &Bs[cur ^ 1][offB[p]]);
    }
    const unsigned short* Ac = As[cur];
    const unsigned short* Bc = Bs[cur];
#pragma unroll
    for (int kc = 0; kc < 2; ++kc) {
      bf16x8 af[4], bfr[2];
#pragma unroll
      for (int i = 0; i < 4; ++i)
        af[i] = *(const bf16x8*)&Ac[(wy * 64 + i * 16 + l15) * 64 + ((kc * 4 + quad) ^ xr) * 8];
#pragma unroll
      for (int j = 0; j < 2; ++j)
        bfr[j] = *(const bf16x8*)&Bc[(wx * 32 + j * 16 + l15) * 64 + ((kc * 4 + quad) ^ xr) * 8];
#pragma unroll
      for (int i = 0; i < 4; ++i)
#pragma unroll
        for (int j = 0; j < 2; ++j)
          acc[i][j] = __builtin_amdgcn_mfma_f32_16x16x32_bf16(af[i], bfr[j], acc[i][j], 0, 0, 0);
    }
  }

#pragma unroll
  for (int i = 0; i < 4; ++i) {
    const int row = m0 + wy * 64 + i * 16 + quad * 4;
#pragma unroll
    for (int j = 0; j < 2; ++j) {
      const int col = n0 + wx * 32 + j * 16 + l15;
      const float bv = bias[col];
#pragma unroll
      for (int r = 0; r < 4; ++r)
        Cf[(size_t)(row + r) * N + col] = acc[i][j][r] + bv;
    }
  }
}

// ---------------- flash attention v19: 8-wave q x kv split (R26) -----------
// Block = 8 waves (wq 0..3 x wk 0..1), 512 thr; grid (bh 32, y 32). Wave:
// 16 q x 32 kv. Plain dbuf __syncthreads staging (R27's counted-vmcnt was
// neutral-negative; reverted). Combine via dead Ks/Vs.
__global__ __launch_bounds__(512, 6) void attn_fwd(const unsigned short* __restrict__ qkv,
                                                   const unsigned short* __restrict__ vt,
                                                   unsigned short* __restrict__ o) {
  __shared__ unsigned short Ks[2][64 * 64];
  __shared__ unsigned short Vs[2][64 * 64];
  __shared__ unsigned short pbuf[8][16 * 40];  // [wave][16 q x (32+8) kv]
  const int tid  = threadIdx.x;
  const int lane = tid & 63;
  const int w    = tid >> 6;          // 8 waves
  const int wq   = w & 3;             // q-quarter (16 q)
  const int wk   = w >> 2;            // kv-half (32 kv)
  const int l15  = lane & 15, quad = lane >> 4;
  const int xr   = l15 & 7;
  const int bh = blockIdx.x, b = bh >> 4, h = bh & 15;
  const int y  = (int)blockIdx.y;
  const int qt = (y < 16) ? y : 47 - y;  // per-CU balanced (R21)
  const int q0 = qt * 64;
  const int T = qt + 1;
  const int qs = q0 + wq * 16;        // this wave's q base (16 rows)

  // DMA staging: 512 chunks per 64x64 tile / 512 threads = 1/thread/array.
  const int r  = tid >> 3;
  const int sc = ((tid & 7) ^ (r & 7)) * 8;
  const unsigned short* gKd = qkv + (size_t)(b * 2048 + r) * 3072 + 1024 + h * 64 + sc;
  const unsigned short* gVd = vt + (size_t)(bh * 64 + r) * 2048 + sc;
  const int doff = tid * 8;

  const unsigned short* qr = qkv + (size_t)(b * 2048 + qs + l15) * 3072 + h * 64;
  const bf16x8 bq[2] = { *(const bf16x8*)(qr + quad * 8),
                         *(const bf16x8*)(qr + 32 + quad * 8) };

  bf16x8 vones;
#pragma unroll
  for (int k = 0; k < 8; ++k) vones[k] = (short)0x3F80;  // bf16 1.0

  f32x4 acc[4];      // [d-tile], PARTIAL over this wave's kv-half
#pragma unroll
  for (int j = 0; j < 4; ++j) acc[j] = (f32x4){0.f, 0.f, 0.f, 0.f};
  f32x4 accL = (f32x4){0.f, 0.f, 0.f, 0.f};

  unsigned short* P = pbuf[w];

  // prologue: DMA tile 0 -> buf 0
  gl_lds16(gKd, &Ks[0][doff]);
  gl_lds16(gVd, &Vs[0][doff]);

  for (int t = 0; t < T; ++t) {
    __syncthreads();  // drains DMA for buf(t&1)
    const int cur = t & 1;
    if (t + 1 < T) {
      const size_t ko = (size_t)(t + 1) * 64 * 3072;
      const int vo = (t + 1) * 64;
      gl_lds16(gKd + ko, &Ks[cur ^ 1][doff]);
      gl_lds16(gVd + vo, &Vs[cur ^ 1][doff]);
    }
    const unsigned short* Kc = Ks[cur];
    const unsigned short* Vc = Vs[cur];
    const int kv0 = t * 64 + wk * 32;   // this wave's kv base

    // ---- S^T[kv][q] = K Q^T, this wave's 32 kv x 16 q ----
    f32x4 st[2];
#pragma unroll
    for (int n = 0; n < 2; ++n) {
      const int row = wk * 32 + n * 16 + l15;
      const bf16x8 kA0 = *(const bf16x8*)&Kc[row * 64 + ((quad) ^ xr) * 8];
      const bf16x8 kA1 = *(const bf16x8*)&Kc[row * 64 + ((4 + quad) ^ xr) * 8];
      f32x4 z = (f32x4){0.f, 0.f, 0.f, 0.f};
      z = __builtin_amdgcn_mfma_f32_16x16x32_bf16(kA0, bq[0], z, 0, 0, 0);
      z = __builtin_amdgcn_mfma_f32_16x16x32_bf16(kA1, bq[1], z, 0, 0, 0);
      st[n] = z;
    }
    // ---- V^T A-frags for this kv-half ----
    bf16x8 av[4];
#pragma unroll
    for (int j = 0; j < 4; ++j) {
      const int row = j * 16 + l15;
      av[j] = *(const bf16x8*)&Vc[row * 64 + ((wk * 4 + quad) ^ xr) * 8];
    }
    // ---- mask/exp + P write ----
    if (kv0 + 31 > qs) {
      const int qrow = qs + l15;
#pragma unroll
      for (int n = 0; n < 2; ++n)
#pragma unroll
        for (int rr = 0; rr < 4; ++rr)
          if (kv0 + n * 16 + quad * 4 + rr > qrow) st[n][rr] = -1e30f;
    }
#pragma unroll
    for (int n = 0; n < 2; ++n) {
#pragma unroll
      for (int rr = 0; rr < 4; ++rr) st[n][rr] = __expf(st[n][rr]);
      u16x4 pw;
      pw[0] = f2b_trunc(st[n][0]); pw[1] = f2b_trunc(st[n][1]);
      pw[2] = f2b_trunc(st[n][2]); pw[3] = f2b_trunc(st[n][3]);
      *(u16x4*)&P[l15 * 40 + n * 16 + quad * 4] = pw;
    }
    // ---- Pr + PV (K=32 contraction) ----
    {
      const bf16x8 bp = *(const bf16x8*)&P[l15 * 40 + quad * 8];
      accL = __builtin_amdgcn_mfma_f32_16x16x32_bf16(vones, bp, accL, 0, 0, 0);
#pragma unroll
      for (int j = 0; j < 4; ++j)
        acc[j] = __builtin_amdgcn_mfma_f32_16x16x32_bf16(av[j], bp, acc[j], 0, 0, 0);
    }
  }

  // ---- cross-wave kv-half combine (once per block; K/V buffers dead) ----
  __syncthreads();
  float* cmbA = (float*)&Ks[0][0];   // 16 frags x 1KB = 16KB = Ks
  float* cmbL = (float*)&Vs[0][0];   // 4 x 64 floats = 1KB
  if (wk == 1) {
    cmbL[wq * 64 + lane] = accL[0];
#pragma unroll
    for (int j = 0; j < 4; ++j)
      *(f32x4*)&cmbA[((wq * 4 + j) << 8) + lane * 4] = acc[j];
  }
  __syncthreads();
  if (wk == 0) {
    const float lsum = accL[0] + cmbL[wq * 64 + lane];
    const float inv = 1.0f / lsum;
    const int qrow = qs + l15;
    unsigned short* orow = o + (size_t)(b * 2048 + qrow) * 1024 + h * 64;
#pragma unroll
    for (int j = 0; j < 4; ++j) {
      const f32x4 oth = *(const f32x4*)&cmbA[((wq * 4 + j) << 8) + lane * 4];
      u16x4 ov;
      ov[0] = f2b((acc[j][0] + oth[0]) * inv);
      ov[1] = f2b((acc[j][1] + oth[1]) * inv);
      ov[2] = f2b((acc[j][2] + oth[2]) * inv);
      ov[3] = f2b((acc[j][3] + oth[3]) * inv);
      *(u16x4*)(orow + j * 16 + quad * 4) = ov;
    }
  }
}

// ---------------------------------------------------------------------------
extern "C" void kernel_launch(void* const* d_in, const int* in_sizes, int n_in,
                              void* d_out, int out_size, void* d_ws, size_t ws_size,
                              hipStream_t stream) {
  const float* x       = (const float*)d_in[0];
  // d_in[1] = mask: causal tril by construction; implemented analytically.
  const float* w_qkv_w = (const float*)d_in[2];
  const float* w_qkv_b = (const float*)d_in[3];
  const float* w_o_w   = (const float*)d_in[4];
  const float* w_o_b   = (const float*)d_in[5];
  float* out = (float*)d_out;

  unsigned short* ws    = (unsigned short*)d_ws;
  unsigned short* xb    = ws;                                  // 4096*1024
  unsigned short* wqb   = xb   + (size_t)4096 * 1024;          // 3072*1024
  unsigned short* wob   = wqb  + (size_t)3072 * 1024;          // 1024*1024
  unsigned short* qkvb  = wob  + (size_t)1024 * 1024;          // 4096*3072
  unsigned short* vtb   = qkvb + (size_t)4096 * 3072;          // 2048*2048
  unsigned short* attnb = vtb  + (size_t)2048 * 2048;          // 4096*1024

  cvt_all<<<8192, 256, 0, stream>>>(x, w_qkv_w, w_o_w, xb, wqb, wob);
  gemm_bt<<<dim3(24, 32), 256, 0, stream>>>(xb, wqb, w_qkv_b, qkvb, vtb, 4096, 3072, 1024, 1024);
  attn_fwd<<<dim3(32, 32), 512, 0, stream>>>(qkvb, vtb, attnb);
  gemm_bt64<<<dim3(16, 32), 256, 0, stream>>>(attnb, wob, w_o_b, out, 4096, 1024, 1024);
}